// Round 3
// baseline (724.560 us; speedup 1.0000x reference)
//
#include <hip/hip_runtime.h>
#include <math.h>

#define Bn 4
#define Dn 512
#define Sn 2048
#define Ln 8921
#define Lpad 8960   // Ln rounded up to 128 (and to 256)

typedef short bf16x8 __attribute__((ext_vector_type(8)));
typedef float f32x4 __attribute__((ext_vector_type(4)));

__device__ __forceinline__ float elu1(float x) {
    return x > 0.f ? x : expm1f(x);
}

// f32 -> bf16 round-to-nearest-even, result in low 16 bits
__device__ __forceinline__ unsigned f2bf(float f) {
    unsigned u = __float_as_uint(f);
    u += 0x7FFFu + ((u >> 16) & 1u);
    return u >> 16;
}
__device__ __forceinline__ unsigned pack2(float a, float b) {
    return f2bf(a) | (f2bf(b) << 16);
}
// truncating pack (fallback path only, R2-proven)
__device__ __forceinline__ unsigned pack_bf_trunc(float lo, float hi) {
    return __builtin_amdgcn_perm(__float_as_uint(hi), __float_as_uint(lo), 0x07060302u);
}
__device__ __forceinline__ void gld_lds16(const void* g, void* l) {
    __builtin_amdgcn_global_load_lds((const __attribute__((address_space(1))) int*)g,
                                     (__attribute__((address_space(3))) int*)l, 16, 0, 0);
}

// ---------------------------------------------------------------------------
// H [B][D][S] f32 -> Ht [B][S][D] bf16 (LDS 64x64 tile transpose)
// ---------------------------------------------------------------------------
__global__ __launch_bounds__(256) void h_transpose(const float* __restrict__ H,
                                                   short* __restrict__ Ht) {
    int b = blockIdx.z;
    int s0 = blockIdx.x * 64, d0 = blockIdx.y * 64;
    __shared__ float tile[64][65];
    int t = threadIdx.x;
    int r = t >> 4, c4 = (t & 15) * 4;
    const float* Hb = H + (size_t)b * Dn * Sn;
#pragma unroll
    for (int i = 0; i < 4; ++i) {
        float4 v = *(const float4*)(Hb + (size_t)(d0 + i * 16 + r) * Sn + s0 + c4);
        *(float4*)&tile[i * 16 + r][c4] = v;  // tile[d][s]
    }
    __syncthreads();
#pragma unroll
    for (int i = 0; i < 4; ++i) {
        int srow = i * 16 + r;
        float v0 = tile[c4 + 0][srow], v1 = tile[c4 + 1][srow];
        float v2 = tile[c4 + 2][srow], v3 = tile[c4 + 3][srow];
        uint2 o = make_uint2(pack2(v0, v1), pack2(v2, v3));
        *(uint2*)(Ht + ((size_t)b * Sn + s0 + srow) * Dn + d0 + c4) = o;
    }
}

// ---------------------------------------------------------------------------
// plain f32 -> bf16 cvt (n8 = elems/8, exact multiple)
// ---------------------------------------------------------------------------
__global__ __launch_bounds__(256) void f32_to_bf16(const float* __restrict__ src,
                                                   short* __restrict__ dst, int n8) {
    int id = blockIdx.x * 256 + threadIdx.x;
    if (id >= n8) return;
    const float* s = src + (size_t)id * 8;
    float4 a = *(const float4*)s;
    float4 b = *(const float4*)(s + 4);
    uint4 o = {pack2(a.x, a.y), pack2(a.z, a.w), pack2(b.x, b.y), pack2(b.z, b.w)};
    *(uint4*)(dst + (size_t)id * 8) = o;
}

// Q f32 [Ln][Dn] -> bf16 [Lpad][Dn], pad rows zeroed
__global__ __launch_bounds__(256) void q_to_bf16(const float* __restrict__ Q,
                                                 short* __restrict__ Qb) {
    int id = blockIdx.x * 256 + threadIdx.x;  // Lpad*64 ids, 8 elems each
    int row = id >> 6, c = (id & 63) * 8;
    uint4 o = {0, 0, 0, 0};
    if (row < Ln) {
        const float* src = Q + (size_t)row * Dn + c;
        float4 a = *(const float4*)src;
        float4 b = *(const float4*)(src + 4);
        o.x = pack2(a.x, a.y); o.y = pack2(a.z, a.w);
        o.z = pack2(b.x, b.y); o.w = pack2(b.z, b.w);
    }
    *(uint4*)(Qb + (size_t)id * 8) = o;
}

// ---------------------------------------------------------------------------
// Old 128x128 NT GEMM (kept for K/V producers + fallback path).
// ---------------------------------------------------------------------------
template <int OUT_BF16, int EPI>
__global__ __launch_bounds__(256) void gemm_nt(const short* __restrict__ A,
                                               const short* __restrict__ B,
                                               const float* __restrict__ bias,
                                               void* __restrict__ Out,
                                               int K, int lda, int ldb, int ldo,
                                               int mmax,
                                               long bA, long bB, long bO) {
    const int b  = blockIdx.z;
    const int n0 = blockIdx.x * 128;
    const int m0 = blockIdx.y * 128;
    __shared__ short lA[128 * 32];
    __shared__ short lB[128 * 32];
    const int t = threadIdx.x;
    const int lane = t & 63, w = t >> 6;
    const int wm = (w & 1) * 64, wn = (w >> 1) * 64;
    const int quad = lane >> 4, l15 = lane & 15;
    f32x4 acc[4][4] = {};
    const short* Ab = A + (size_t)bA * b + (size_t)m0 * lda;
    const short* Bb = B + (size_t)bB * b + (size_t)n0 * ldb;
    const int sr = t >> 2, ss = (t & 3) * 8;

    for (int k0 = 0; k0 < K; k0 += 32) {
        gld_lds16(Ab + (size_t)sr * lda + k0 + ss,        lA + t * 8);
        gld_lds16(Ab + (size_t)(sr + 64) * lda + k0 + ss, lA + 2048 + t * 8);
        gld_lds16(Bb + (size_t)sr * ldb + k0 + ss,        lB + t * 8);
        gld_lds16(Bb + (size_t)(sr + 64) * ldb + k0 + ss, lB + 2048 + t * 8);
        __syncthreads();
        bf16x8 af[4], bfr[4];
#pragma unroll
        for (int i = 0; i < 4; ++i)
            af[i] = *(const bf16x8*)&lA[(wm + i * 16 + l15) * 32 + quad * 8];
#pragma unroll
        for (int j = 0; j < 4; ++j)
            bfr[j] = *(const bf16x8*)&lB[(wn + j * 16 + l15) * 32 + quad * 8];
#pragma unroll
        for (int i = 0; i < 4; ++i)
#pragma unroll
            for (int j = 0; j < 4; ++j)
                acc[i][j] = __builtin_amdgcn_mfma_f32_16x16x32_bf16(af[i], bfr[j], acc[i][j], 0, 0, 0);
        __syncthreads();
    }

#pragma unroll
    for (int i = 0; i < 4; ++i) {
        int mb = m0 + wm + i * 16 + quad * 4;
#pragma unroll
        for (int r = 0; r < 4; ++r) {
            int m = mb + r;
            if (m < mmax) {
                float bm = (EPI == 2) ? bias[m] : 0.f;
#pragma unroll
                for (int j = 0; j < 4; ++j) {
                    int col = n0 + wn + j * 16 + l15;
                    float v = acc[i][j][r];
                    if (EPI == 1) v = elu1(v + bias[col]);
                    if (EPI == 2) v = elu1(v + bm);
                    if (OUT_BF16)
                        ((short*)Out)[(size_t)bO * b + (size_t)m * ldo + col] = (short)f2bf(v);
                    else
                        ((float*)Out)[(size_t)bO * b + (size_t)m * ldo + col] = v;
                }
            }
        }
    }
}

// ---------------------------------------------------------------------------
// 256xBN NT GEMM, BK=32, 8 waves (512 thr), quad-buffered LDS,
// counted vmcnt, 2-phase m201-style cadence per K-tile, setprio on MFMA,
// chunk-XOR swizzled LDS, bijective XCD chunk-swizzle on the grid.
//
// BN=256: waves 2m x 4n, wave tile 128x64, LDS 128 KiB. (E GEMM)
// BN=128: waves 4m x 2n, wave tile  64x64, LDS  96 KiB. (C GEMM, 2x blocks)
//
// Pipeline invariants (R2-proven skeleton + added phase barriers):
//   - STAGE(k+3) issued during iter k (A-half in phase0, B-half in phase1)
//     into slot (k+3)&3, whose reads completed before iter k-1's last
//     pre-MFMA lgkmcnt(0)+barrier.
//   - top of iter k: lgkmcnt(0), vmcnt(2T) (T = loads/thread/tile) ->
//     tile k's T loads landed; barrier -> visible to all waves.
//   - peel: vmcnt(T) at k==NK-2, vmcnt(0) at k==NK-1.
// LDS chunk swizzle: 16B-chunk c = row*4 + quad, position p = c ^ ((c>>3)&3)
// applied on BOTH the gld_lds global source and the ds_read offset.
// ---------------------------------------------------------------------------
template <int OUT_BF16, int BN>
__global__ __launch_bounds__(512, 2) void gemm_ntp(const short* __restrict__ A,
                                                   const short* __restrict__ B,
                                                   void* __restrict__ Out,
                                                   int K, int lda, int ldb, int ldo,
                                                   int mmax,
                                                   long bA, long bB, long bO) {
    constexpr int NWN   = BN / 64;       // waves along N
    constexpr int WSPAN = 32 * NWN;      // wave M-span
    constexpr int WMF   = 2 * NWN;       // A fragments per wave
    constexpr int BCH   = BN * 4;        // B 16B-chunks per slot
    constexpr int SLOT  = 8192 + BN * 32;  // shorts per slot
    constexpr int TPB   = 2 + BN / 128;  // loads per thread per tile
    __shared__ short lds[4 * SLOT];

    // --- bijective XCD chunk swizzle (T1): XCD x gets a contiguous chunk ---
    int GX = gridDim.x, GY = gridDim.y;
    int nwg = GX * GY * gridDim.z;
    int lin = blockIdx.x + GX * (blockIdx.y + GY * blockIdx.z);
    int wid = lin;
    if ((nwg & 7) == 0) wid = (lin & 7) * (nwg >> 3) + (lin >> 3);
    int bx = wid % GX; wid /= GX;
    int by = wid % GY;
    int bz = wid / GY;

    const int b  = bz;
    const int n0 = bx * BN;
    const int m0 = by * 256;
    const int t = threadIdx.x;           // 0..511
    const int lane = t & 63, w = t >> 6; // 8 waves
    const int wn = w % NWN, wm = w / NWN;
    const int quad = lane >> 4, l15 = lane & 15;
    const int xr = (l15 >> 1) & 3;       // swizzle key = row bits[2:1]

    const short* Ab = A + (size_t)bA * b + (size_t)m0 * lda;
    const short* Bb = B + (size_t)bB * b + (size_t)n0 * ldb;

    // stage addressing (pre-swizzled global source, linear LDS dest per lane)
    const short* srcA[2]; int dstA[2];
#pragma unroll
    for (int i = 0; i < 2; ++i) {
        int p = i * 512 + t;
        int g = p ^ ((p >> 3) & 3);
        srcA[i] = Ab + (size_t)(g >> 2) * lda + (g & 3) * 8;
        dstA[i] = p * 8;
    }
    const short* srcB[2]; int dstB[2];
#pragma unroll
    for (int i = 0; i < BCH / 512; ++i) {
        int p = i * 512 + t;
        int g = p ^ ((p >> 3) & 3);
        srcB[i] = Bb + (size_t)(g >> 2) * ldb + (g & 3) * 8;
        dstB[i] = 8192 + p * 8;
    }

    // fragment read offsets (shorts within slot), swizzled
    int offA[WMF], offB[4];
#pragma unroll
    for (int m = 0; m < WMF; ++m) {
        int c = (wm * WSPAN + m * 16 + l15) * 4 + quad;
        offA[m] = (c ^ xr) * 8;
    }
#pragma unroll
    for (int j = 0; j < 4; ++j) {
        int c = (wn * 64 + j * 16 + l15) * 4 + quad;
        offB[j] = 8192 + (c ^ xr) * 8;
    }

    f32x4 acc[WMF][4] = {};
    const int NK = K >> 5;

    auto STAGE_A = [&](int kt) {
        const int slot = (kt & 3) * SLOT;
        const int ko = kt * 32;
        gld_lds16(srcA[0] + ko, &lds[slot + dstA[0]]);
        gld_lds16(srcA[1] + ko, &lds[slot + dstA[1]]);
    };
    auto STAGE_B = [&](int kt) {
        const int slot = (kt & 3) * SLOT;
        const int ko = kt * 32;
        gld_lds16(srcB[0] + ko, &lds[slot + dstB[0]]);
        if constexpr (BN == 256) gld_lds16(srcB[1] + ko, &lds[slot + dstB[1]]);
    };

    STAGE_A(0); STAGE_B(0);
    STAGE_A(1); STAGE_B(1);
    STAGE_A(2); STAGE_B(2);

    for (int k = 0; k < NK; ++k) {
        // ---- iter top: slot k staged+visible; prev iter's reads drained ----
        asm volatile("s_waitcnt lgkmcnt(0)" ::: "memory");
        if constexpr (TPB == 4) {
            if (k < NK - 2)       asm volatile("s_waitcnt vmcnt(8)" ::: "memory");
            else if (k == NK - 2) asm volatile("s_waitcnt vmcnt(4)" ::: "memory");
            else                  asm volatile("s_waitcnt vmcnt(0)" ::: "memory");
        } else {
            if (k < NK - 2)       asm volatile("s_waitcnt vmcnt(6)" ::: "memory");
            else if (k == NK - 2) asm volatile("s_waitcnt vmcnt(3)" ::: "memory");
            else                  asm volatile("s_waitcnt vmcnt(0)" ::: "memory");
        }
        __builtin_amdgcn_s_barrier();
        asm volatile("" ::: "memory");
        const short* sl = &lds[(k & 3) * SLOT];

        // ---- phase 0: B frags + first half of A frags; A-stage of k+3 ----
        bf16x8 af[WMF], bfv[4];
#pragma unroll
        for (int j = 0; j < 4; ++j) bfv[j] = *(const bf16x8*)(sl + offB[j]);
#pragma unroll
        for (int m = 0; m < WMF / 2; ++m) af[m] = *(const bf16x8*)(sl + offA[m]);
        if (k + 3 < NK) STAGE_A(k + 3);
        asm volatile("s_waitcnt lgkmcnt(0)" ::: "memory");
        __builtin_amdgcn_s_barrier();
        __builtin_amdgcn_s_setprio(1);
#pragma unroll
        for (int m = 0; m < WMF / 2; ++m)
#pragma unroll
            for (int j = 0; j < 4; ++j)
                acc[m][j] = __builtin_amdgcn_mfma_f32_16x16x32_bf16(af[m], bfv[j], acc[m][j], 0, 0, 0);
        __builtin_amdgcn_s_setprio(0);
        __builtin_amdgcn_s_barrier();

        // ---- phase 1: second half of A frags; B-stage of k+3 ----
#pragma unroll
        for (int m = WMF / 2; m < WMF; ++m) af[m] = *(const bf16x8*)(sl + offA[m]);
        if (k + 3 < NK) STAGE_B(k + 3);
        asm volatile("s_waitcnt lgkmcnt(0)" ::: "memory");
        __builtin_amdgcn_s_barrier();
        __builtin_amdgcn_s_setprio(1);
#pragma unroll
        for (int m = WMF / 2; m < WMF; ++m)
#pragma unroll
            for (int j = 0; j < 4; ++j)
                acc[m][j] = __builtin_amdgcn_mfma_f32_16x16x32_bf16(af[m], bfv[j], acc[m][j], 0, 0, 0);
        __builtin_amdgcn_s_setprio(0);
        // iter-end barrier is the next iteration's top barrier
    }

#pragma unroll
    for (int m = 0; m < WMF; ++m) {
        int mb = m0 + wm * WSPAN + m * 16 + quad * 4;
#pragma unroll
        for (int r = 0; r < 4; ++r) {
            int mm = mb + r;
            if (mm < mmax) {
#pragma unroll
                for (int j = 0; j < 4; ++j) {
                    int col = n0 + wn * 64 + j * 16 + l15;
                    float v = acc[m][j][r];
                    if (OUT_BF16)
                        ((short*)Out)[(size_t)bO * b + (size_t)mm * ldo + col] = (short)f2bf(v);
                    else
                        ((float*)Out)[(size_t)bO * b + (size_t)mm * ldo + col] = v;
                }
            }
        }
    }
}

// ---------------------------------------------------------------------------
// Softmax (primary): reads bf16 E in ws, writes f32 A (output) + bf16 A in place
// ---------------------------------------------------------------------------
__global__ __launch_bounds__(256) void softmax_bf16(short* __restrict__ EA,
                                                    float* __restrict__ Aout) {
    int row = blockIdx.x;  // 0..B*Ln-1
    int b = row / Ln, l = row - b * Ln;
    short* pe = EA + ((size_t)b * Lpad + l) * Sn;
    float* pa = Aout + (size_t)row * Sn;
    int t = threadIdx.x;
    uint4 raw = *(const uint4*)(pe + t * 8);
    unsigned pw[4] = {raw.x, raw.y, raw.z, raw.w};
    float v[8];
#pragma unroll
    for (int q = 0; q < 4; ++q) {
        v[2 * q]     = __uint_as_float(pw[q] << 16);
        v[2 * q + 1] = __uint_as_float(pw[q] & 0xFFFF0000u);
    }
    float m = v[0];
#pragma unroll
    for (int i = 1; i < 8; ++i) m = fmaxf(m, v[i]);
#pragma unroll
    for (int off = 32; off >= 1; off >>= 1) m = fmaxf(m, __shfl_xor(m, off));
    __shared__ float sm[4], ssum[4];
    int lane = t & 63, wv = t >> 6;
    if (lane == 0) sm[wv] = m;
    __syncthreads();
    m = fmaxf(fmaxf(sm[0], sm[1]), fmaxf(sm[2], sm[3]));
    float s = 0.f;
#pragma unroll
    for (int i = 0; i < 8; ++i) {
        v[i] = expf(v[i] - m);
        s += v[i];
    }
#pragma unroll
    for (int off = 32; off >= 1; off >>= 1) s += __shfl_xor(s, off);
    if (lane == 0) ssum[wv] = s;
    __syncthreads();
    s = ssum[0] + ssum[1] + ssum[2] + ssum[3];
    float inv = 1.f / s;
#pragma unroll
    for (int i = 0; i < 8; ++i) v[i] *= inv;
    float4 o0 = {v[0], v[1], v[2], v[3]};
    float4 o1 = {v[4], v[5], v[6], v[7]};
    *(float4*)(pa + t * 8)     = o0;
    *(float4*)(pa + t * 8 + 4) = o1;
    uint4 ob = {pack2(v[0], v[1]), pack2(v[2], v[3]), pack2(v[4], v[5]), pack2(v[6], v[7])};
    *(uint4*)(pe + t * 8) = ob;
}

// Softmax (fallback): f32 in place on the A output region
__global__ __launch_bounds__(256) void softmax_f32(float* __restrict__ E) {
    size_t row = blockIdx.x;
    float* p = E + row * (size_t)Sn;
    int t = threadIdx.x;
    float4 u0 = *(const float4*)(p + t * 8);
    float4 u1 = *(const float4*)(p + t * 8 + 4);
    float v[8] = {u0.x, u0.y, u0.z, u0.w, u1.x, u1.y, u1.z, u1.w};
    float m = v[0];
#pragma unroll
    for (int i = 1; i < 8; ++i) m = fmaxf(m, v[i]);
#pragma unroll
    for (int off = 32; off >= 1; off >>= 1) m = fmaxf(m, __shfl_xor(m, off));
    __shared__ float sm[4], ssum[4];
    int lane = t & 63, wv = t >> 6;
    if (lane == 0) sm[wv] = m;
    __syncthreads();
    m = fmaxf(fmaxf(sm[0], sm[1]), fmaxf(sm[2], sm[3]));
    float s = 0.f;
#pragma unroll
    for (int i = 0; i < 8; ++i) {
        v[i] = expf(v[i] - m);
        s += v[i];
    }
#pragma unroll
    for (int off = 32; off >= 1; off >>= 1) s += __shfl_xor(s, off);
    if (lane == 0) ssum[wv] = s;
    __syncthreads();
    s = ssum[0] + ssum[1] + ssum[2] + ssum[3];
    float inv = 1.f / s;
#pragma unroll
    for (int i = 0; i < 8; ++i) v[i] *= inv;
    float4 o0 = {v[0], v[1], v[2], v[3]};
    float4 o1 = {v[4], v[5], v[6], v[7]};
    *(float4*)(p + t * 8)     = o0;
    *(float4*)(p + t * 8 + 4) = o1;
}

// ---------------------------------------------------------------------------
// Fallback C GEMM (R2 structure, f32 A staging; grid x=n for A reuse)
// ---------------------------------------------------------------------------
__global__ __launch_bounds__(256) void c_mfma_f32(const float* __restrict__ A,
                                                  const short* __restrict__ Vt,
                                                  float* __restrict__ C) {
    const int b  = blockIdx.z;
    const int n0 = blockIdx.x * 128;
    const int m0 = blockIdx.y * 128;
    __shared__ short lA[128 * 32];
    __shared__ short lB[128 * 32];
    const int t = threadIdx.x;
    const int lane = t & 63, w = t >> 6;
    const int wm = (w & 1) * 64, wn = (w >> 1) * 64;
    const int quad = lane >> 4, l15 = lane & 15;
    f32x4 acc[4][4] = {};
    const float* Ab = A + (size_t)b * Ln * Sn;
    const short* Bb = Vt + (size_t)b * Dn * Sn + (size_t)n0 * Sn;
    const int ar = t >> 1, ah = (t & 1) * 16;
    const int br = t >> 2, bs = (t & 3) * 8;
    const int am = m0 + ar;
    const bool arow_ok = (am < Ln);
    const float* asrc0 = Ab + (size_t)am * Sn + ah;

    for (int s0 = 0; s0 < Sn; s0 += 32) {
        gld_lds16(Bb + (size_t)br * Sn + s0 + bs,        lB + t * 8);
        gld_lds16(Bb + (size_t)(br + 64) * Sn + s0 + bs, lB + 2048 + t * 8);
        unsigned p[8] = {0, 0, 0, 0, 0, 0, 0, 0};
        if (arow_ok) {
            const float* src = asrc0 + s0;
            float4 f0 = *(const float4*)(src);
            float4 f1 = *(const float4*)(src + 4);
            float4 f2 = *(const float4*)(src + 8);
            float4 f3 = *(const float4*)(src + 12);
            p[0] = pack_bf_trunc(f0.x, f0.y); p[1] = pack_bf_trunc(f0.z, f0.w);
            p[2] = pack_bf_trunc(f1.x, f1.y); p[3] = pack_bf_trunc(f1.z, f1.w);
            p[4] = pack_bf_trunc(f2.x, f2.y); p[5] = pack_bf_trunc(f2.z, f2.w);
            p[6] = pack_bf_trunc(f3.x, f3.y); p[7] = pack_bf_trunc(f3.z, f3.w);
        }
        *(uint4*)&lA[ar * 32 + ah]     = *(uint4*)&p[0];
        *(uint4*)&lA[ar * 32 + ah + 8] = *(uint4*)&p[4];
        __syncthreads();
        bf16x8 af[4], bfr[4];
#pragma unroll
        for (int i = 0; i < 4; ++i)
            af[i] = *(const bf16x8*)&lA[(wm + i * 16 + l15) * 32 + quad * 8];
#pragma unroll
        for (int j = 0; j < 4; ++j)
            bfr[j] = *(const bf16x8*)&lB[(wn + j * 16 + l15) * 32 + quad * 8];
#pragma unroll
        for (int i = 0; i < 4; ++i)
#pragma unroll
            for (int j = 0; j < 4; ++j)
                acc[i][j] = __builtin_amdgcn_mfma_f32_16x16x32_bf16(af[i], bfr[j], acc[i][j], 0, 0, 0);
        __syncthreads();
    }

#pragma unroll
    for (int i = 0; i < 4; ++i) {
        int mb = m0 + wm + i * 16 + quad * 4;
#pragma unroll
        for (int r = 0; r < 4; ++r) {
            int m = mb + r;
            if (m < Ln) {
                float* dst = C + (size_t)b * Ln * Dn + (size_t)m * Dn + n0 + wn;
#pragma unroll
                for (int j = 0; j < 4; ++j) dst[j * 16 + l15] = acc[i][j][r];
            }
        }
    }
}

// ---------------------------------------------------------------------------
extern "C" void kernel_launch(void* const* d_in, const int* in_sizes, int n_in,
                              void* d_out, int out_size, void* d_ws, size_t ws_size,
                              hipStream_t stream) {
    const float* H  = (const float*)d_in[0];  // [B, D, S]
    const float* Wk = (const float*)d_in[1];  // [D, D]
    const float* bk = (const float*)d_in[2];  // [D]
    const float* Wv = (const float*)d_in[3];  // [D, D]
    const float* bv = (const float*)d_in[4];  // [D]
    const float* Q  = (const float*)d_in[5];  // [L, D]

    float* out  = (float*)d_out;
    float* Cout = out;                          // [B, L, D]
    float* Aout = out + (size_t)Bn * Ln * Dn;   // [B, L, S]

    // ws layout (shorts):
    short* Vt  = (short*)d_ws;                        // [B][Dn][Sn]
    short* Kb  = Vt + (size_t)Bn * Dn * Sn;           // [B][Sn][Dn]
    short* Qb  = Kb + (size_t)Bn * Sn * Dn;           // [Lpad][Dn]
    short* EAb = Qb + (size_t)Lpad * Dn;              // [B][Lpad][Sn]  (primary)
    short* Ht  = EAb;                                 // [B][Sn][Dn], dead before EAb written
    short* Wkb = Ht + (size_t)Bn * Sn * Dn;           // [Dn][Dn], dead before EAb
    short* Wvb = Wkb + (size_t)Dn * Dn;               // [Dn][Dn]

    size_t need_primary =
        2 * ((size_t)Bn * Dn * Sn + (size_t)Bn * Sn * Dn + (size_t)Lpad * Dn +
             (size_t)Bn * Lpad * Sn);
    bool big = ws_size >= need_primary;

    // 1) precision prep
    h_transpose<<<dim3(Sn / 64, Dn / 64, Bn), 256, 0, stream>>>(H, Ht);
    f32_to_bf16<<<(Dn * Dn / 8 + 255) / 256, 256, 0, stream>>>(Wk, Wkb, Dn * Dn / 8);
    f32_to_bf16<<<(Dn * Dn / 8 + 255) / 256, 256, 0, stream>>>(Wv, Wvb, Dn * Dn / 8);
    q_to_bf16<<<(Lpad * 64) / 256, 256, 0, stream>>>(Q, Qb);

    // 2) K[b][s][o] = elu(Ht·Wk^T + bk)   (M=Sn, N=Dn, K=Dn)
    gemm_nt<1, 1><<<dim3(Dn / 128, Sn / 128, Bn), 256, 0, stream>>>(
        Ht, Wkb, bk, Kb, Dn, Dn, Dn, Dn, Sn,
        (long)Sn * Dn, 0L, (long)Sn * Dn);

    // 3) Vt[b][o][s] = elu(Wv·Ht^T + bv)  (M=Dn, N=Sn, K=Dn)
    gemm_nt<1, 2><<<dim3(Sn / 128, Dn / 128, Bn), 256, 0, stream>>>(
        Wvb, Ht, bv, Vt, Dn, Dn, Dn, Sn, Dn,
        0L, (long)Sn * Dn, (long)Dn * Sn);

    if (big) {
        // 4) E bf16 -> EAb   (M=Lpad, N=Sn, K=Dn), 256x256 2-phase pipelined
        gemm_ntp<1, 256><<<dim3(Sn / 256, Lpad / 256, Bn), 512, 0, stream>>>(
            Qb, Kb, EAb, Dn, Dn, Dn, Sn, Lpad,
            0L, (long)Sn * Dn, (long)Lpad * Sn);
        // 5) softmax: bf16 E -> f32 A out + bf16 A in place
        softmax_bf16<<<Bn * Ln, 256, 0, stream>>>(EAb, Aout);
        // 6) C = A·V   (M=Lpad, N=Dn, K=Sn), 256x128 2-phase pipelined
        gemm_ntp<0, 128><<<dim3(Dn / 128, Lpad / 256, Bn), 512, 0, stream>>>(
            EAb, Vt, Cout, Sn, Sn, Sn, Dn, Ln,
            (long)Lpad * Sn, (long)Dn * Sn, (long)Ln * Dn);
    } else {
        // fallback: f32 E in A-output region
        gemm_nt<0, 0><<<dim3(Sn / 128, Lpad / 128, Bn), 256, 0, stream>>>(
            Qb, Kb, nullptr, Aout, Dn, Dn, Dn, Sn, Ln,
            0L, (long)Sn * Dn, (long)Ln * Sn);
        softmax_f32<<<Bn * Ln, 256, 0, stream>>>(Aout);
        c_mfma_f32<<<dim3(Dn / 128, Lpad / 128, Bn), 256, 0, stream>>>(Aout, Vt, Cout);
    }
}